// Round 2
// baseline (313.299 us; speedup 1.0000x reference)
//
#include <hip/hip_runtime.h>
#include <math.h>

#define N_NODES 50000
#define N_EDGES 800000
#define N_GRAPHS 512
#define IN_DIM 128
#define HID_DIM 256
#define EMB_DIM 128
#define EPS 1e-5f
#define ELLW 64
#define NGROUP 8
#define GROUPN 6250
#define BLK_PER_GROUP 256
#define SCAT_BLOCKS (NGROUP * BLK_PER_GROUP)
#define EPB ((N_EDGES + BLK_PER_GROUP - 1) / BLK_PER_GROUP)
#define F2B_N (N_NODES * IN_DIM / 4)
#define F2B_BLOCKS ((F2B_N + 255) / 256)
#define TW1_BLOCKS ((HID_DIM * IN_DIM + 255) / 256)
#define NSLOTS 128   // partial-stat slots for layer-2 sum/sumsq (atomic chain ~98/address)

typedef __attribute__((ext_vector_type(8))) short bf16x8;
typedef __attribute__((ext_vector_type(4))) float f32x4;

static __device__ __forceinline__ unsigned short f2b(float f) {
    unsigned u = __float_as_uint(f);
    return (unsigned short)((u + 0x7fffu + ((u >> 16) & 1u)) >> 16);
}
static __device__ __forceinline__ float b2f(unsigned short h) {
    return __uint_as_float(((unsigned)h) << 16);
}
static __device__ __forceinline__ float dinv_of(int d) {
    return rsqrtf((float)(min(d, ELLW) + 1));
}

// ---------- merged: ELL scatter (XCD-partitioned) + x->bf16 + W1 transpose ----------
__global__ void __launch_bounds__(256) scatter_convert(const int* __restrict__ src,
                                                       const int* __restrict__ dst,
                                                       int* __restrict__ fill,
                                                       int* __restrict__ col,
                                                       const float* __restrict__ x,
                                                       unsigned short* __restrict__ xbf,
                                                       const float* __restrict__ W1,
                                                       unsigned short* __restrict__ W1t) {
    int b = blockIdx.x;
    if (b < SCAT_BLOCKS) {
        int g = b & 7;
        int bs = b >> 3;
        int lo = g * GROUPN;
        int hi = lo + GROUPN;
        int e_end = min((bs + 1) * EPB, N_EDGES);
        for (int e = bs * EPB + threadIdx.x; e < e_end; e += 256) {
            int d = dst[e];
            if (d >= lo && d < hi) {
                int pos = atomicAdd(&fill[d], 1);
                pos = min(pos, ELLW - 1);
                col[(d << 6) + pos] = src[e];
            }
        }
    } else if (b < SCAT_BLOCKS + F2B_BLOCKS) {
        int i = (b - SCAT_BLOCKS) * 256 + threadIdx.x;
        if (i < F2B_N) {
            float4 v = ((const float4*)x)[i];
            ushort4 o;
            o.x = f2b(v.x); o.y = f2b(v.y); o.z = f2b(v.z); o.w = f2b(v.w);
            ((ushort4*)xbf)[i] = o;
        }
    } else {
        int j = (b - SCAT_BLOCKS - F2B_BLOCKS) * 256 + threadIdx.x;
        if (j < HID_DIM * IN_DIM) {
            int n = j >> 7;
            int k = j & 127;
            W1t[j] = f2b(W1[k * HID_DIM + n]);
        }
    }
}

// ---------- wave-per-node aggregation over ELL, quarter-wave 16B row gathers ----------
// STATS (layer 2 only): block-reduce per-channel sum/sumsq of the fp32 outputs into
// NSLOTS partial buffers (slot = blockIdx & (NSLOTS-1)); finalized inside segmax.
static __device__ __forceinline__ void acc8(float* acc, uint4 r, float w) {
    const unsigned* u = (const unsigned*)&r;
#pragma unroll
    for (int k = 0; k < 4; ++k) {
        float lo = __uint_as_float((u[k] & 0xFFFFu) << 16);
        float hi = __uint_as_float(u[k] & 0xFFFF0000u);
        acc[2 * k]     += w * lo;
        acc[2 * k + 1] += w * hi;
    }
}

template <bool RELU, bool OUT_BF, bool BIAS, bool STATS>
__global__ void __launch_bounds__(256) aggw_kernel(const unsigned short* __restrict__ h,
                                                   const int* __restrict__ deg,
                                                   const int* __restrict__ col,
                                                   const float* __restrict__ bias,
                                                   void* __restrict__ y,
                                                   float* __restrict__ sumP,
                                                   float* __restrict__ sqP) {
    __shared__ float sv[STATS ? 4 : 1][STATS ? 128 : 1];
    int tid = threadIdx.x;
    int lane = tid & 63;
    int wid = tid >> 6;
    int v = blockIdx.x * 4 + wid;
    int g = lane >> 4;
    int p = lane & 15;

    int beg = v << 6;
    int dcl = min(deg[v], ELLW);
    int end = beg + dcl;
    float acc[8] = {};

    for (int e = beg; e < end; e += 16) {
        int i0 = e + g, i1 = e + 4 + g, i2 = e + 8 + g, i3 = e + 12 + g;
        int c0 = min(i0, end - 1), c1 = min(i1, end - 1);
        int c2 = min(i2, end - 1), c3 = min(i3, end - 1);
        int u0 = col[c0], u1 = col[c1], u2 = col[c2], u3 = col[c3];
        float w0 = (i0 < end) ? dinv_of(deg[u0]) : 0.f;
        float w1 = (i1 < end) ? dinv_of(deg[u1]) : 0.f;
        float w2 = (i2 < end) ? dinv_of(deg[u2]) : 0.f;
        float w3 = (i3 < end) ? dinv_of(deg[u3]) : 0.f;
        uint4 d0 = *(const uint4*)(h + (size_t)u0 * 128 + p * 8);
        uint4 d1 = *(const uint4*)(h + (size_t)u1 * 128 + p * 8);
        uint4 d2 = *(const uint4*)(h + (size_t)u2 * 128 + p * 8);
        uint4 d3 = *(const uint4*)(h + (size_t)u3 * 128 + p * 8);
        acc8(acc, d0, w0);
        acc8(acc, d1, w1);
        acc8(acc, d2, w2);
        acc8(acc, d3, w3);
    }

#pragma unroll
    for (int k = 0; k < 8; ++k) {
        float a = acc[k];
        a += __shfl_xor(a, 16, 64);
        a += __shfl_xor(a, 32, 64);
        acc[k] = a;
    }

    if (g == 0) {
        uint4 selfr = *(const uint4*)(h + (size_t)v * 128 + p * 8);
        const unsigned* su = (const unsigned*)&selfr;
        float dv = rsqrtf((float)(dcl + 1));
        float dv2 = dv * dv;
        float o[8];
#pragma unroll
        for (int k = 0; k < 4; ++k) {
            float lo = __uint_as_float((su[k] & 0xFFFFu) << 16);
            float hi = __uint_as_float(su[k] & 0xFFFF0000u);
            o[2 * k]     = dv * acc[2 * k]     + lo * dv2;
            o[2 * k + 1] = dv * acc[2 * k + 1] + hi * dv2;
        }
        if (BIAS) {
            float4 bv0 = *(const float4*)&bias[p * 8];
            float4 bv1 = *(const float4*)&bias[p * 8 + 4];
            o[0] += bv0.x; o[1] += bv0.y; o[2] += bv0.z; o[3] += bv0.w;
            o[4] += bv1.x; o[5] += bv1.y; o[6] += bv1.z; o[7] += bv1.w;
        }
        if (RELU) {
#pragma unroll
            for (int k = 0; k < 8; ++k) o[k] = fmaxf(o[k], 0.f);
        }
        if (OUT_BF) {
            uint4 packed;
            unsigned* pu = (unsigned*)&packed;
#pragma unroll
            for (int k = 0; k < 4; ++k)
                pu[k] = (unsigned)f2b(o[2 * k]) | ((unsigned)f2b(o[2 * k + 1]) << 16);
            *(uint4*)((unsigned short*)y + (size_t)v * 128 + p * 8) = packed;
        } else {
            float* yf = (float*)y + (size_t)v * 128 + p * 8;
            *(float4*)yf = make_float4(o[0], o[1], o[2], o[3]);
            *(float4*)(yf + 4) = make_float4(o[4], o[5], o[6], o[7]);
        }
        if (STATS) {
#pragma unroll
            for (int k = 0; k < 8; ++k) sv[wid][p * 8 + k] = o[k];
        }
    }

    if (STATS) {
        __syncthreads();   // uniform: STATS is compile-time
        if (tid < 128) {
            float s = 0.f, q = 0.f;
#pragma unroll
            for (int w = 0; w < 4; ++w) {
                float val = sv[w][tid];
                s += val;
                q += val * val;
            }
            int slot = blockIdx.x & (NSLOTS - 1);
            atomicAdd(&sumP[slot * 128 + tid], s);
            atomicAdd(&sqP[slot * 128 + tid], q);
        }
    }
}

// ---------- MFMA bf16 GEMM (64x64, LDT=40) with optional fused column stats ----------
template <bool RELU, bool STATS>
__global__ void __launch_bounds__(256) mfma_gemm_kernel(const unsigned short* __restrict__ A,
                                                        const unsigned short* __restrict__ Bt,
                                                        const float* __restrict__ bias,
                                                        unsigned short* __restrict__ C,
                                                        float* __restrict__ sums,
                                                        float* __restrict__ sumsqs,
                                                        int M, int N, int K) {
    const int LDT = 40;  // 32 + 8 pad (ushorts)
    __shared__ unsigned short As[64 * LDT];
    __shared__ unsigned short Bs[64 * LDT];
    int tid = threadIdx.x;
    int bm = blockIdx.x * 64;
    int bn = blockIdx.y * 64;
    int lr = tid >> 2;
    int lc = (tid & 3) * 8;
    int lane = tid & 63;
    int w = tid >> 6;
    int wr = (w >> 1) * 32, wc = (w & 1) * 32;
    int l15 = lane & 15, q = lane >> 4;

    f32x4 acc[2][2] = {};
    bool arow_ok = (bm + lr) < M;
    const unsigned short* Aptr = A + (size_t)(bm + lr) * K + lc;
    const unsigned short* Bptr = Bt + (size_t)(bn + lr) * K + lc;

    for (int k0 = 0; k0 < K; k0 += 32) {
        uint4 av = arow_ok ? *(const uint4*)(Aptr + k0) : make_uint4(0u, 0u, 0u, 0u);
        uint4 bv = *(const uint4*)(Bptr + k0);
        *(uint4*)&As[lr * LDT + lc] = av;
        *(uint4*)&Bs[lr * LDT + lc] = bv;
        __syncthreads();
        bf16x8 a0 = *(const bf16x8*)&As[(wr + 0 + l15) * LDT + q * 8];
        bf16x8 a1 = *(const bf16x8*)&As[(wr + 16 + l15) * LDT + q * 8];
        bf16x8 b0 = *(const bf16x8*)&Bs[(wc + 0 + l15) * LDT + q * 8];
        bf16x8 b1 = *(const bf16x8*)&Bs[(wc + 16 + l15) * LDT + q * 8];
        acc[0][0] = __builtin_amdgcn_mfma_f32_16x16x32_bf16(a0, b0, acc[0][0], 0, 0, 0);
        acc[0][1] = __builtin_amdgcn_mfma_f32_16x16x32_bf16(a0, b1, acc[0][1], 0, 0, 0);
        acc[1][0] = __builtin_amdgcn_mfma_f32_16x16x32_bf16(a1, b0, acc[1][0], 0, 0, 0);
        acc[1][1] = __builtin_amdgcn_mfma_f32_16x16x32_bf16(a1, b1, acc[1][1], 0, 0, 0);
        __syncthreads();
    }

    float scol[2] = {0.f, 0.f};
    float qcol[2] = {0.f, 0.f};
#pragma unroll
    for (int mi = 0; mi < 2; ++mi)
#pragma unroll
        for (int ni = 0; ni < 2; ++ni) {
            int colc = bn + wc + ni * 16 + l15;
            float bv = bias ? bias[colc] : 0.f;
#pragma unroll
            for (int r = 0; r < 4; ++r) {
                int row = bm + wr + mi * 16 + q * 4 + r;
                if (row < M) {
                    float vv = acc[mi][ni][r] + bv;
                    if (RELU) vv = fmaxf(vv, 0.f);
                    C[(size_t)row * N + colc] = f2b(vv);
                    if (STATS) { scol[ni] += vv; qcol[ni] += vv * vv; }
                }
            }
        }

    if (STATS) {
        __shared__ float sred[4][2][16];
        __shared__ float qred[4][2][16];
#pragma unroll
        for (int ni = 0; ni < 2; ++ni) {
            float s = scol[ni], qq = qcol[ni];
            s += __shfl_xor(s, 16, 64);
            s += __shfl_xor(s, 32, 64);
            qq += __shfl_xor(qq, 16, 64);
            qq += __shfl_xor(qq, 32, 64);
            if (lane < 16) { sred[w][ni][l15] = s; qred[w][ni][l15] = qq; }
        }
        __syncthreads();
        if (tid < 64) {
            int par = (tid >> 5) & 1;
            int ni = (tid >> 4) & 1;
            int l = tid & 15;
            atomicAdd(&sums[bn + tid], sred[par][ni][l] + sred[par + 2][ni][l]);
            atomicAdd(&sumsqs[bn + tid], qred[par][ni][l] + qred[par + 2][ni][l]);
        }
    }
}

// ---------- fold BN1 into W2 (8 blocks: 16 output rows each, 16-way K split) ----------
__global__ void __launch_bounds__(256) prep2_kernel(const float* __restrict__ sum1,
                                                    const float* __restrict__ sumsq1,
                                                    const float* __restrict__ gamma1,
                                                    const float* __restrict__ beta1,
                                                    const float* __restrict__ W2,
                                                    unsigned short* __restrict__ W2pt,
                                                    float* __restrict__ bc2) {
    __shared__ float a1s[HID_DIM], s1s[HID_DIM];
    __shared__ float bp[16][17];
    int t = threadIdx.x;
    {
        float m = sum1[t] * (1.f / N_NODES);
        float var = sumsq1[t] * (1.f / N_NODES) - m * m;
        float a = gamma1[t] * rsqrtf(var + EPS);
        a1s[t] = a;
        s1s[t] = beta1[t] - m * a;
    }
    __syncthreads();
    int row = blockIdx.x * 16 + (t & 15);
    int ks = t >> 4;
    float bacc = 0.f;
    unsigned short wloc[16];
#pragma unroll
    for (int j = 0; j < 16; ++j) {
        int k = ks * 16 + j;
        float wv = W2[k * EMB_DIM + row];
        wloc[j] = f2b(a1s[k] * wv);
        bacc += s1s[k] * wv;
    }
    *(uint4*)&W2pt[(size_t)row * HID_DIM + ks * 16]     = *(uint4*)&wloc[0];
    *(uint4*)&W2pt[(size_t)row * HID_DIM + ks * 16 + 8] = *(uint4*)&wloc[8];
    bp[t & 15][ks] = bacc;
    __syncthreads();
    if (t < 16) {
        float s = 0.f;
#pragma unroll
        for (int g = 0; g < 16; ++g) s += bp[t][g];
        bc2[blockIdx.x * 16 + t] = s;
    }
}

// ---------- segmented max per graph; finalizes layer-2 partial stats in-block ----------
__global__ void __launch_bounds__(128) segmax_kernel(const float* __restrict__ y,
                                                     const float* __restrict__ sumP,
                                                     const float* __restrict__ sqP,
                                                     const float* __restrict__ gamma2,
                                                     const float* __restrict__ beta2,
                                                     const int* __restrict__ batch,
                                                     float* __restrict__ out) {
    __shared__ int sh[2];
    int g = blockIdx.x;
    int c = threadIdx.x;
    float s2 = 0.f, q2 = 0.f;
#pragma unroll 8
    for (int j = 0; j < NSLOTS; ++j) {
        s2 += sumP[j * 128 + c];
        q2 += sqP[j * 128 + c];
    }
    float mch = s2 * (1.f / N_NODES);
    float var = q2 * (1.f / N_NODES) - mch * mch;
    float ac = gamma2[c] * rsqrtf(var + EPS);
    float sc = beta2[c] - mch * ac;
    if (threadIdx.x == 0) {
        int lo = 0, hi = N_NODES;
        while (lo < hi) { int mid = (lo + hi) >> 1; if (batch[mid] < g) lo = mid + 1; else hi = mid; }
        sh[0] = lo;
        hi = N_NODES;
        while (lo < hi) { int mid = (lo + hi) >> 1; if (batch[mid] < g + 1) lo = mid + 1; else hi = mid; }
        sh[1] = lo;
    }
    __syncthreads();
    int beg = sh[0], end = sh[1];
    float m = -INFINITY;
    for (int v = beg; v < end; ++v) {
        m = fmaxf(m, fmaf(ac, y[(size_t)v * EMB_DIM + c], sc));
    }
    out[(size_t)g * EMB_DIM + c] = m;
}

extern "C" void kernel_launch(void* const* d_in, const int* in_sizes, int n_in,
                              void* d_out, int out_size, void* d_ws, size_t ws_size,
                              hipStream_t stream) {
    const float* x      = (const float*)d_in[0];
    const int*   ei     = (const int*)d_in[1];
    const int*   batch  = (const int*)d_in[2];
    const float* W1     = (const float*)d_in[3];
    const float* b1     = (const float*)d_in[4];
    const float* gamma1 = (const float*)d_in[5];
    const float* beta1  = (const float*)d_in[6];
    const float* W2     = (const float*)d_in[7];
    const float* b2     = (const float*)d_in[8];
    const float* gamma2 = (const float*)d_in[9];
    const float* beta2  = (const float*)d_in[10];
    float* out = (float*)d_out;

    char* ws = (char*)d_ws;
    size_t off = 0;
    auto alloc = [&](size_t bytes) -> char* {
        char* p = ws + off;
        off = (off + bytes + 255) & ~(size_t)255;
        return p;
    };
    int*   fill   = (int*)alloc((size_t)N_NODES * 4);
    float* stats  = (float*)alloc(1024 * 4);                       // sum1/sumsq1 for layer 1
    float* sumP   = (float*)alloc((size_t)NSLOTS * 128 * 4);       // layer-2 partial sums
    float* sqP    = (float*)alloc((size_t)NSLOTS * 128 * 4);       // layer-2 partial sumsqs
    size_t zbytes = off;
    int*   col    = (int*)alloc((size_t)N_NODES * ELLW * 4);
    float* bc2    = (float*)alloc((size_t)EMB_DIM * 4);
    unsigned short* W1t  = (unsigned short*)alloc((size_t)HID_DIM * IN_DIM * 2);
    unsigned short* W2pt = (unsigned short*)alloc((size_t)HID_DIM * EMB_DIM * 2);
    unsigned short* xbf  = (unsigned short*)alloc((size_t)N_NODES * IN_DIM * 2);   // also y2 region
    unsigned short* axbf = (unsigned short*)alloc((size_t)N_NODES * IN_DIM * 2);
    unsigned short* y1bf = (unsigned short*)alloc((size_t)N_NODES * HID_DIM * 2);
    unsigned short* gbf  = (unsigned short*)alloc((size_t)N_NODES * EMB_DIM * 2);
    float* y2 = (float*)xbf;  // xbf+axbf dead by layer 2; contiguous 25.6 MB
    (void)ws_size; (void)in_sizes; (void)n_in; (void)out_size;

    const int* src  = ei;
    const int* dstp = ei + N_EDGES;

    hipMemsetAsync(ws, 0, zbytes, stream);   // zero fill + stats + partials in one call

    // merged: ELL scatter + x->bf16 + W1 transpose
    scatter_convert<<<SCAT_BLOCKS + F2B_BLOCKS + TW1_BLOCKS, 256, 0, stream>>>(
        src, dstp, fill, col, x, xbf, W1, W1t);

    // Layer 1: ax = A x (bf16), y1 = relu(ax@W1 + b1) (bf16) with fused column stats
    aggw_kernel<false, true, false, false><<<N_NODES / 4, 256, 0, stream>>>(
        xbf, fill, col, nullptr, axbf, nullptr, nullptr);
    dim3 g1((N_NODES + 63) / 64, HID_DIM / 64);
    mfma_gemm_kernel<true, true><<<g1, 256, 0, stream>>>(axbf, W1t, b1, y1bf,
                                                         stats, stats + 256,
                                                         N_NODES, HID_DIM, IN_DIM);

    // Fold BN1 into W2 (transposed bf16) + pre-aggregation column bias bc2
    prep2_kernel<<<8, 256, 0, stream>>>(stats, stats + 256, gamma1, beta1, W2, W2pt, bc2);

    // Layer 2: g = y1@W2p + bc2 (bf16), y2 = relu(A g + b2) (fp32) with fused partial stats
    dim3 g2((N_NODES + 63) / 64, EMB_DIM / 64);
    mfma_gemm_kernel<false, false><<<g2, 256, 0, stream>>>(y1bf, W2pt, bc2, gbf,
                                                           nullptr, nullptr,
                                                           N_NODES, EMB_DIM, HID_DIM);
    aggw_kernel<true, false, true, true><<<N_NODES / 4, 256, 0, stream>>>(
        gbf, fill, col, b2, y2, sumP, sqP);

    // fused BN2-finalize (reduce NSLOTS partials) + per-graph segmented max
    segmax_kernel<<<N_GRAPHS, 128, 0, stream>>>(y2, sumP, sqP,
                                                gamma2, beta2, batch, out);
}

// Round 3
// 285.712 us; speedup vs baseline: 1.0966x; 1.0966x over previous
//
#include <hip/hip_runtime.h>
#include <math.h>

#define N_NODES 50000
#define N_EDGES 800000
#define N_GRAPHS 512
#define IN_DIM 128
#define HID_DIM 256
#define EMB_DIM 128
#define EPS 1e-5f
#define ELLW 64
#define NGROUP 8
#define GROUPN 6250
#define BLK_PER_GROUP 256
#define SCAT_BLOCKS (NGROUP * BLK_PER_GROUP)
#define EPB ((N_EDGES + BLK_PER_GROUP - 1) / BLK_PER_GROUP)
#define F2B_N (N_NODES * IN_DIM / 4)
#define F2B_BLOCKS ((F2B_N + 255) / 256)
#define TW1_BLOCKS ((HID_DIM * IN_DIM + 255) / 256)
#define NSLOTS 128   // partial-stat slots (layer-2 aggw stats)
#define GSLOTS 128   // partial-stat slots (layer-1 gemm stats; chain 782 -> ~6)

typedef __attribute__((ext_vector_type(8))) short bf16x8;
typedef __attribute__((ext_vector_type(4))) float f32x4;

static __device__ __forceinline__ unsigned short f2b(float f) {
    unsigned u = __float_as_uint(f);
    return (unsigned short)((u + 0x7fffu + ((u >> 16) & 1u)) >> 16);
}
static __device__ __forceinline__ float b2f(unsigned short h) {
    return __uint_as_float(((unsigned)h) << 16);
}
static __device__ __forceinline__ float dinv_of(int d) {
    return rsqrtf((float)(min(d, ELLW) + 1));
}

// ---------- merged: ELL scatter (XCD-partitioned) + x->bf16 + W1 transpose ----------
__global__ void __launch_bounds__(256) scatter_convert(const int* __restrict__ src,
                                                       const int* __restrict__ dst,
                                                       int* __restrict__ fill,
                                                       int* __restrict__ col,
                                                       const float* __restrict__ x,
                                                       unsigned short* __restrict__ xbf,
                                                       const float* __restrict__ W1,
                                                       unsigned short* __restrict__ W1t) {
    int b = blockIdx.x;
    if (b < SCAT_BLOCKS) {
        int g = b & 7;
        int bs = b >> 3;
        int lo = g * GROUPN;
        int hi = lo + GROUPN;
        int e_end = min((bs + 1) * EPB, N_EDGES);
        for (int e = bs * EPB + threadIdx.x; e < e_end; e += 256) {
            int d = dst[e];
            if (d >= lo && d < hi) {
                int pos = atomicAdd(&fill[d], 1);
                pos = min(pos, ELLW - 1);
                col[(d << 6) + pos] = src[e];
            }
        }
    } else if (b < SCAT_BLOCKS + F2B_BLOCKS) {
        int i = (b - SCAT_BLOCKS) * 256 + threadIdx.x;
        if (i < F2B_N) {
            float4 v = ((const float4*)x)[i];
            ushort4 o;
            o.x = f2b(v.x); o.y = f2b(v.y); o.z = f2b(v.z); o.w = f2b(v.w);
            ((ushort4*)xbf)[i] = o;
        }
    } else {
        int j = (b - SCAT_BLOCKS - F2B_BLOCKS) * 256 + threadIdx.x;
        if (j < HID_DIM * IN_DIM) {
            int n = j >> 7;
            int k = j & 127;
            W1t[j] = f2b(W1[k * HID_DIM + n]);
        }
    }
}

// ---------- wave-per-node aggregation over ELL, quarter-wave 16B row gathers ----------
static __device__ __forceinline__ void acc8(float* acc, uint4 r, float w) {
    const unsigned* u = (const unsigned*)&r;
#pragma unroll
    for (int k = 0; k < 4; ++k) {
        float lo = __uint_as_float((u[k] & 0xFFFFu) << 16);
        float hi = __uint_as_float(u[k] & 0xFFFF0000u);
        acc[2 * k]     += w * lo;
        acc[2 * k + 1] += w * hi;
    }
}

template <bool RELU, bool OUT_BF, bool BIAS, bool STATS>
__global__ void __launch_bounds__(256) aggw_kernel(const unsigned short* __restrict__ h,
                                                   const int* __restrict__ deg,
                                                   const int* __restrict__ col,
                                                   const float* __restrict__ bias,
                                                   void* __restrict__ y,
                                                   float* __restrict__ sumP,
                                                   float* __restrict__ sqP) {
    __shared__ float sv[STATS ? 4 : 1][STATS ? 128 : 1];
    int tid = threadIdx.x;
    int lane = tid & 63;
    int wid = tid >> 6;
    int v = blockIdx.x * 4 + wid;
    int g = lane >> 4;
    int p = lane & 15;

    int beg = v << 6;
    int dcl = min(deg[v], ELLW);
    int end = beg + dcl;
    float acc[8] = {};

    for (int e = beg; e < end; e += 16) {
        int i0 = e + g, i1 = e + 4 + g, i2 = e + 8 + g, i3 = e + 12 + g;
        int c0 = min(i0, end - 1), c1 = min(i1, end - 1);
        int c2 = min(i2, end - 1), c3 = min(i3, end - 1);
        int u0 = col[c0], u1 = col[c1], u2 = col[c2], u3 = col[c3];
        float w0 = (i0 < end) ? dinv_of(deg[u0]) : 0.f;
        float w1 = (i1 < end) ? dinv_of(deg[u1]) : 0.f;
        float w2 = (i2 < end) ? dinv_of(deg[u2]) : 0.f;
        float w3 = (i3 < end) ? dinv_of(deg[u3]) : 0.f;
        uint4 d0 = *(const uint4*)(h + (size_t)u0 * 128 + p * 8);
        uint4 d1 = *(const uint4*)(h + (size_t)u1 * 128 + p * 8);
        uint4 d2 = *(const uint4*)(h + (size_t)u2 * 128 + p * 8);
        uint4 d3 = *(const uint4*)(h + (size_t)u3 * 128 + p * 8);
        acc8(acc, d0, w0);
        acc8(acc, d1, w1);
        acc8(acc, d2, w2);
        acc8(acc, d3, w3);
    }

#pragma unroll
    for (int k = 0; k < 8; ++k) {
        float a = acc[k];
        a += __shfl_xor(a, 16, 64);
        a += __shfl_xor(a, 32, 64);
        acc[k] = a;
    }

    if (g == 0) {
        uint4 selfr = *(const uint4*)(h + (size_t)v * 128 + p * 8);
        const unsigned* su = (const unsigned*)&selfr;
        float dv = rsqrtf((float)(dcl + 1));
        float dv2 = dv * dv;
        float o[8];
#pragma unroll
        for (int k = 0; k < 4; ++k) {
            float lo = __uint_as_float((su[k] & 0xFFFFu) << 16);
            float hi = __uint_as_float(su[k] & 0xFFFF0000u);
            o[2 * k]     = dv * acc[2 * k]     + lo * dv2;
            o[2 * k + 1] = dv * acc[2 * k + 1] + hi * dv2;
        }
        if (BIAS) {
            float4 bv0 = *(const float4*)&bias[p * 8];
            float4 bv1 = *(const float4*)&bias[p * 8 + 4];
            o[0] += bv0.x; o[1] += bv0.y; o[2] += bv0.z; o[3] += bv0.w;
            o[4] += bv1.x; o[5] += bv1.y; o[6] += bv1.z; o[7] += bv1.w;
        }
        if (RELU) {
#pragma unroll
            for (int k = 0; k < 8; ++k) o[k] = fmaxf(o[k], 0.f);
        }
        if (OUT_BF) {
            uint4 packed;
            unsigned* pu = (unsigned*)&packed;
#pragma unroll
            for (int k = 0; k < 4; ++k)
                pu[k] = (unsigned)f2b(o[2 * k]) | ((unsigned)f2b(o[2 * k + 1]) << 16);
            *(uint4*)((unsigned short*)y + (size_t)v * 128 + p * 8) = packed;
        } else {
            float* yf = (float*)y + (size_t)v * 128 + p * 8;
            *(float4*)yf = make_float4(o[0], o[1], o[2], o[3]);
            *(float4*)(yf + 4) = make_float4(o[4], o[5], o[6], o[7]);
        }
        if (STATS) {
#pragma unroll
            for (int k = 0; k < 8; ++k) sv[wid][p * 8 + k] = o[k];
        }
    }

    if (STATS) {
        __syncthreads();   // uniform: STATS is compile-time
        if (tid < 128) {
            float s = 0.f, q = 0.f;
#pragma unroll
            for (int w = 0; w < 4; ++w) {
                float val = sv[w][tid];
                s += val;
                q += val * val;
            }
            int slot = blockIdx.x & (NSLOTS - 1);
            atomicAdd(&sumP[slot * 128 + tid], s);
            atomicAdd(&sqP[slot * 128 + tid], q);
        }
    }
}

// ---------- MFMA bf16 GEMM (64x64, LDT=40), register-prefetched K loop ----------
// STATS: per-channel sum/sumsq partials into [GSLOTS][N] (slot = blockIdx.x & (GSLOTS-1));
// reduced later in prep2. Avoids the 782-deep same-address atomic chains.
template <bool RELU, bool STATS>
__global__ void __launch_bounds__(256) mfma_gemm_kernel(const unsigned short* __restrict__ A,
                                                        const unsigned short* __restrict__ Bt,
                                                        const float* __restrict__ bias,
                                                        unsigned short* __restrict__ C,
                                                        float* __restrict__ sums,
                                                        float* __restrict__ sumsqs,
                                                        int M, int N, int K) {
    const int LDT = 40;  // 32 + 8 pad (ushorts)
    __shared__ unsigned short As[64 * LDT];
    __shared__ unsigned short Bs[64 * LDT];
    int tid = threadIdx.x;
    int bm = blockIdx.x * 64;
    int bn = blockIdx.y * 64;
    int lr = tid >> 2;
    int lc = (tid & 3) * 8;
    int lane = tid & 63;
    int w = tid >> 6;
    int wr = (w >> 1) * 32, wc = (w & 1) * 32;
    int l15 = lane & 15, q = lane >> 4;

    f32x4 acc[2][2] = {};
    bool arow_ok = (bm + lr) < M;
    const unsigned short* Aptr = A + (size_t)(bm + lr) * K + lc;
    const unsigned short* Bptr = Bt + (size_t)(bn + lr) * K + lc;

    // prologue: fetch k0=0 tile into registers
    uint4 av = arow_ok ? *(const uint4*)(Aptr) : make_uint4(0u, 0u, 0u, 0u);
    uint4 bv = *(const uint4*)(Bptr);

    for (int k0 = 0; k0 < K; k0 += 32) {
        *(uint4*)&As[lr * LDT + lc] = av;
        *(uint4*)&Bs[lr * LDT + lc] = bv;
        __syncthreads();
        if (k0 + 32 < K) {   // prefetch next tile; latency hides under ds_read+MFMA
            av = arow_ok ? *(const uint4*)(Aptr + k0 + 32) : make_uint4(0u, 0u, 0u, 0u);
            bv = *(const uint4*)(Bptr + k0 + 32);
        }
        bf16x8 a0 = *(const bf16x8*)&As[(wr + 0 + l15) * LDT + q * 8];
        bf16x8 a1 = *(const bf16x8*)&As[(wr + 16 + l15) * LDT + q * 8];
        bf16x8 b0 = *(const bf16x8*)&Bs[(wc + 0 + l15) * LDT + q * 8];
        bf16x8 b1 = *(const bf16x8*)&Bs[(wc + 16 + l15) * LDT + q * 8];
        acc[0][0] = __builtin_amdgcn_mfma_f32_16x16x32_bf16(a0, b0, acc[0][0], 0, 0, 0);
        acc[0][1] = __builtin_amdgcn_mfma_f32_16x16x32_bf16(a0, b1, acc[0][1], 0, 0, 0);
        acc[1][0] = __builtin_amdgcn_mfma_f32_16x16x32_bf16(a1, b0, acc[1][0], 0, 0, 0);
        acc[1][1] = __builtin_amdgcn_mfma_f32_16x16x32_bf16(a1, b1, acc[1][1], 0, 0, 0);
        __syncthreads();
    }

    float scol[2] = {0.f, 0.f};
    float qcol[2] = {0.f, 0.f};
#pragma unroll
    for (int mi = 0; mi < 2; ++mi)
#pragma unroll
        for (int ni = 0; ni < 2; ++ni) {
            int colc = bn + wc + ni * 16 + l15;
            float bv2 = bias ? bias[colc] : 0.f;
#pragma unroll
            for (int r = 0; r < 4; ++r) {
                int row = bm + wr + mi * 16 + q * 4 + r;
                if (row < M) {
                    float vv = acc[mi][ni][r] + bv2;
                    if (RELU) vv = fmaxf(vv, 0.f);
                    C[(size_t)row * N + colc] = f2b(vv);
                    if (STATS) { scol[ni] += vv; qcol[ni] += vv * vv; }
                }
            }
        }

    if (STATS) {
        __shared__ float sred[4][2][16];
        __shared__ float qred[4][2][16];
#pragma unroll
        for (int ni = 0; ni < 2; ++ni) {
            float s = scol[ni], qq = qcol[ni];
            s += __shfl_xor(s, 16, 64);
            s += __shfl_xor(s, 32, 64);
            qq += __shfl_xor(qq, 16, 64);
            qq += __shfl_xor(qq, 32, 64);
            if (lane < 16) { sred[w][ni][l15] = s; qred[w][ni][l15] = qq; }
        }
        __syncthreads();
        if (tid < 64) {
            int par = (tid >> 5) & 1;
            int ni = (tid >> 4) & 1;
            int l = tid & 15;
            int slot = blockIdx.x & (GSLOTS - 1);
            atomicAdd(&sums[slot * HID_DIM + bn + tid],
                      sred[par][ni][l] + sred[par + 2][ni][l]);
            atomicAdd(&sumsqs[slot * HID_DIM + bn + tid],
                      qred[par][ni][l] + qred[par + 2][ni][l]);
        }
    }
}

// ---------- fold BN1 into W2 (8 blocks); reduces GSLOTS stat partials first ----------
__global__ void __launch_bounds__(256) prep2_kernel(const float* __restrict__ sum1P,
                                                    const float* __restrict__ sumsq1P,
                                                    const float* __restrict__ gamma1,
                                                    const float* __restrict__ beta1,
                                                    const float* __restrict__ W2,
                                                    unsigned short* __restrict__ W2pt,
                                                    float* __restrict__ bc2) {
    __shared__ float a1s[HID_DIM], s1s[HID_DIM];
    __shared__ float bp[16][17];
    int t = threadIdx.x;
    {
        float s = 0.f, q = 0.f;
#pragma unroll 8
        for (int j = 0; j < GSLOTS; ++j) {
            s += sum1P[j * HID_DIM + t];
            q += sumsq1P[j * HID_DIM + t];
        }
        float m = s * (1.f / N_NODES);
        float var = q * (1.f / N_NODES) - m * m;
        float a = gamma1[t] * rsqrtf(var + EPS);
        a1s[t] = a;
        s1s[t] = beta1[t] - m * a;
    }
    __syncthreads();
    int row = blockIdx.x * 16 + (t & 15);
    int ks = t >> 4;
    float bacc = 0.f;
    unsigned short wloc[16];
#pragma unroll
    for (int j = 0; j < 16; ++j) {
        int k = ks * 16 + j;
        float wv = W2[k * EMB_DIM + row];
        wloc[j] = f2b(a1s[k] * wv);
        bacc += s1s[k] * wv;
    }
    *(uint4*)&W2pt[(size_t)row * HID_DIM + ks * 16]     = *(uint4*)&wloc[0];
    *(uint4*)&W2pt[(size_t)row * HID_DIM + ks * 16 + 8] = *(uint4*)&wloc[8];
    bp[t & 15][ks] = bacc;
    __syncthreads();
    if (t < 16) {
        float s = 0.f;
#pragma unroll
        for (int g = 0; g < 16; ++g) s += bp[t][g];
        bc2[blockIdx.x * 16 + t] = s;
    }
}

// ---------- segmented max per graph; finalizes layer-2 partial stats in-block ----------
__global__ void __launch_bounds__(128) segmax_kernel(const float* __restrict__ y,
                                                     const float* __restrict__ sumP,
                                                     const float* __restrict__ sqP,
                                                     const float* __restrict__ gamma2,
                                                     const float* __restrict__ beta2,
                                                     const int* __restrict__ batch,
                                                     float* __restrict__ out) {
    __shared__ int sh[2];
    int g = blockIdx.x;
    int c = threadIdx.x;
    float s2 = 0.f, q2 = 0.f;
#pragma unroll 8
    for (int j = 0; j < NSLOTS; ++j) {
        s2 += sumP[j * 128 + c];
        q2 += sqP[j * 128 + c];
    }
    float mch = s2 * (1.f / N_NODES);
    float var = q2 * (1.f / N_NODES) - mch * mch;
    float ac = gamma2[c] * rsqrtf(var + EPS);
    float sc = beta2[c] - mch * ac;
    if (threadIdx.x == 0) {
        int lo = 0, hi = N_NODES;
        while (lo < hi) { int mid = (lo + hi) >> 1; if (batch[mid] < g) lo = mid + 1; else hi = mid; }
        sh[0] = lo;
        hi = N_NODES;
        while (lo < hi) { int mid = (lo + hi) >> 1; if (batch[mid] < g + 1) lo = mid + 1; else hi = mid; }
        sh[1] = lo;
    }
    __syncthreads();
    int beg = sh[0], end = sh[1];
    float m = -INFINITY;
    for (int v = beg; v < end; ++v) {
        m = fmaxf(m, fmaf(ac, y[(size_t)v * EMB_DIM + c], sc));
    }
    out[(size_t)g * EMB_DIM + c] = m;
}

extern "C" void kernel_launch(void* const* d_in, const int* in_sizes, int n_in,
                              void* d_out, int out_size, void* d_ws, size_t ws_size,
                              hipStream_t stream) {
    const float* x      = (const float*)d_in[0];
    const int*   ei     = (const int*)d_in[1];
    const int*   batch  = (const int*)d_in[2];
    const float* W1     = (const float*)d_in[3];
    const float* b1     = (const float*)d_in[4];
    const float* gamma1 = (const float*)d_in[5];
    const float* beta1  = (const float*)d_in[6];
    const float* W2     = (const float*)d_in[7];
    const float* b2     = (const float*)d_in[8];
    const float* gamma2 = (const float*)d_in[9];
    const float* beta2  = (const float*)d_in[10];
    float* out = (float*)d_out;

    char* ws = (char*)d_ws;
    size_t off = 0;
    auto alloc = [&](size_t bytes) -> char* {
        char* p = ws + off;
        off = (off + bytes + 255) & ~(size_t)255;
        return p;
    };
    int*   fill    = (int*)alloc((size_t)N_NODES * 4);
    float* gsumP   = (float*)alloc((size_t)GSLOTS * HID_DIM * 4);  // layer-1 stat partials
    float* gsqP    = (float*)alloc((size_t)GSLOTS * HID_DIM * 4);
    float* sumP    = (float*)alloc((size_t)NSLOTS * 128 * 4);      // layer-2 stat partials
    float* sqP     = (float*)alloc((size_t)NSLOTS * 128 * 4);
    size_t zbytes = off;
    int*   col    = (int*)alloc((size_t)N_NODES * ELLW * 4);
    float* bc2    = (float*)alloc((size_t)EMB_DIM * 4);
    unsigned short* W1t  = (unsigned short*)alloc((size_t)HID_DIM * IN_DIM * 2);
    unsigned short* W2pt = (unsigned short*)alloc((size_t)HID_DIM * EMB_DIM * 2);
    unsigned short* xbf  = (unsigned short*)alloc((size_t)N_NODES * IN_DIM * 2);   // also y2 region
    unsigned short* axbf = (unsigned short*)alloc((size_t)N_NODES * IN_DIM * 2);
    unsigned short* y1bf = (unsigned short*)alloc((size_t)N_NODES * HID_DIM * 2);
    unsigned short* gbf  = (unsigned short*)alloc((size_t)N_NODES * EMB_DIM * 2);
    float* y2 = (float*)xbf;  // xbf+axbf dead by layer 2; contiguous 25.6 MB
    (void)ws_size; (void)in_sizes; (void)n_in; (void)out_size;

    const int* src  = ei;
    const int* dstp = ei + N_EDGES;

    hipMemsetAsync(ws, 0, zbytes, stream);   // zero fill + all stat partials in one call

    // merged: ELL scatter + x->bf16 + W1 transpose
    scatter_convert<<<SCAT_BLOCKS + F2B_BLOCKS + TW1_BLOCKS, 256, 0, stream>>>(
        src, dstp, fill, col, x, xbf, W1, W1t);

    // Layer 1: ax = A x (bf16), y1 = relu(ax@W1 + b1) (bf16) with slotted column stats
    aggw_kernel<false, true, false, false><<<N_NODES / 4, 256, 0, stream>>>(
        xbf, fill, col, nullptr, axbf, nullptr, nullptr);
    dim3 g1((N_NODES + 63) / 64, HID_DIM / 64);
    mfma_gemm_kernel<true, true><<<g1, 256, 0, stream>>>(axbf, W1t, b1, y1bf,
                                                         gsumP, gsqP,
                                                         N_NODES, HID_DIM, IN_DIM);

    // Fold BN1 into W2 (transposed bf16) + pre-aggregation column bias bc2
    prep2_kernel<<<8, 256, 0, stream>>>(gsumP, gsqP, gamma1, beta1, W2, W2pt, bc2);

    // Layer 2: g = y1@W2p + bc2 (bf16), y2 = relu(A g + b2) (fp32) with slotted stats
    dim3 g2((N_NODES + 63) / 64, EMB_DIM / 64);
    mfma_gemm_kernel<false, false><<<g2, 256, 0, stream>>>(y1bf, W2pt, bc2, gbf,
                                                           nullptr, nullptr,
                                                           N_NODES, EMB_DIM, HID_DIM);
    aggw_kernel<true, false, true, true><<<N_NODES / 4, 256, 0, stream>>>(
        gbf, fill, col, b2, y2, sumP, sqP);

    // fused BN2-finalize (reduce NSLOTS partials) + per-graph segmented max
    segmax_kernel<<<N_GRAPHS, 128, 0, stream>>>(y2, sumP, sqP,
                                                gamma2, beta2, batch, out);
}

// Round 6
// 270.124 us; speedup vs baseline: 1.1598x; 1.0577x over previous
//
#include <hip/hip_runtime.h>
#include <math.h>

#define N_NODES 50000
#define N_EDGES 800000
#define N_GRAPHS 512
#define IN_DIM 128
#define HID_DIM 256
#define EMB_DIM 128
#define EPS 1e-5f
#define ELLW 64
#define NGROUP 8
#define GROUPN 6250
#define BLK_PER_GROUP 256
#define SCAT_BLOCKS (NGROUP * BLK_PER_GROUP)
#define EPV4 ((N_EDGES / 4 + BLK_PER_GROUP - 1) / BLK_PER_GROUP)  // vec4 groups per block
#define F2B_N (N_NODES * IN_DIM / 4)
#define F2B_BLOCKS ((F2B_N + 255) / 256)
#define TW1_BLOCKS ((HID_DIM * IN_DIM + 255) / 256)
#define NSLOTS 128   // partial-stat slots (layer-2 aggw stats)
#define GSLOTS 128   // partial-stat slots (layer-1 gemm stats)

typedef __attribute__((ext_vector_type(8))) short bf16x8;
typedef __attribute__((ext_vector_type(4))) float f32x4;

static __device__ __forceinline__ unsigned short f2b(float f) {
    unsigned u = __float_as_uint(f);
    return (unsigned short)((u + 0x7fffu + ((u >> 16) & 1u)) >> 16);
}
static __device__ __forceinline__ float b2f(unsigned short h) {
    return __uint_as_float(((unsigned)h) << 16);
}
static __device__ __forceinline__ float dinv_of(int d) {
    return rsqrtf((float)(min(d, ELLW) + 1));
}

// ---------- merged: ELL scatter (XCD-partitioned, int4-vectorized scan) + converts ----------
__global__ void __launch_bounds__(256) scatter_convert(const int* __restrict__ src,
                                                       const int* __restrict__ dst,
                                                       int* __restrict__ fill,
                                                       int* __restrict__ col,
                                                       const float* __restrict__ x,
                                                       unsigned short* __restrict__ xbf,
                                                       const float* __restrict__ W1,
                                                       unsigned short* __restrict__ W1t) {
    int b = blockIdx.x;
    if (b < SCAT_BLOCKS) {
        int g = b & 7;
        int bs = b >> 3;
        int lo = g * GROUPN;
        int hi = lo + GROUPN;
        int i_end = min((bs + 1) * EPV4, N_EDGES / 4);
        const int4* dst4 = (const int4*)dst;
        const int4* src4 = (const int4*)src;
        for (int i = bs * EPV4 + threadIdx.x; i < i_end; i += 256) {
            int4 d4 = dst4[i];
            int4 s4 = src4[i];
            if (d4.x >= lo && d4.x < hi) {
                int pos = min(atomicAdd(&fill[d4.x], 1), ELLW - 1);
                col[(d4.x << 6) + pos] = s4.x;
            }
            if (d4.y >= lo && d4.y < hi) {
                int pos = min(atomicAdd(&fill[d4.y], 1), ELLW - 1);
                col[(d4.y << 6) + pos] = s4.y;
            }
            if (d4.z >= lo && d4.z < hi) {
                int pos = min(atomicAdd(&fill[d4.z], 1), ELLW - 1);
                col[(d4.z << 6) + pos] = s4.z;
            }
            if (d4.w >= lo && d4.w < hi) {
                int pos = min(atomicAdd(&fill[d4.w], 1), ELLW - 1);
                col[(d4.w << 6) + pos] = s4.w;
            }
        }
    } else if (b < SCAT_BLOCKS + F2B_BLOCKS) {
        int i = (b - SCAT_BLOCKS) * 256 + threadIdx.x;
        if (i < F2B_N) {
            float4 v = ((const float4*)x)[i];
            ushort4 o;
            o.x = f2b(v.x); o.y = f2b(v.y); o.z = f2b(v.z); o.w = f2b(v.w);
            ((ushort4*)xbf)[i] = o;
        }
    } else {
        int j = (b - SCAT_BLOCKS - F2B_BLOCKS) * 256 + threadIdx.x;
        if (j < HID_DIM * IN_DIM) {
            int n = j >> 7;
            int k = j & 127;
            W1t[j] = f2b(W1[k * HID_DIM + n]);
        }
    }
}

// ---------- wave-per-node ELL aggregation; col/weights register-resident ----------
// One coalesced 256B load gives the full ELL row (1 entry/lane); one 64-wide gather +
// rsqrt gives all weights. The inner loop gets (u,w) via __shfl — only the 16B h-row
// gathers touch memory, removing the col->deg->rsqrt dependent chain per iteration.
static __device__ __forceinline__ void acc8(float* acc, uint4 r, float w) {
    const unsigned* u = (const unsigned*)&r;
#pragma unroll
    for (int k = 0; k < 4; ++k) {
        float lo = __uint_as_float((u[k] & 0xFFFFu) << 16);
        float hi = __uint_as_float(u[k] & 0xFFFF0000u);
        acc[2 * k]     += w * lo;
        acc[2 * k + 1] += w * hi;
    }
}

template <bool RELU, bool OUT_BF, bool BIAS, bool STATS>
__global__ void __launch_bounds__(256) aggw_kernel(const unsigned short* __restrict__ h,
                                                   const int* __restrict__ deg,
                                                   const int* __restrict__ col,
                                                   const float* __restrict__ bias,
                                                   void* __restrict__ y,
                                                   float* __restrict__ sumP,
                                                   float* __restrict__ sqP) {
    __shared__ float sv[STATS ? 4 : 1][STATS ? 128 : 1];
    int tid = threadIdx.x;
    int lane = tid & 63;
    int wid = tid >> 6;
    int v = blockIdx.x * 4 + wid;
    int g = lane >> 4;
    int p = lane & 15;

    int dcl = min(deg[v], ELLW);
    int cv = col[(v << 6) + lane];           // full ELL row, one coalesced load
    int u_l = (lane < dcl) ? cv : v;
    float w_l = (lane < dcl) ? dinv_of(deg[u_l]) : 0.f;

    uint4 selfr = make_uint4(0u, 0u, 0u, 0u);
    if (g == 0) selfr = *(const uint4*)(h + (size_t)v * 128 + p * 8);

    float acc[8] = {};
    for (int base = 0; base < dcl; base += 16) {
        int i0 = base + g, i1 = base + 4 + g, i2 = base + 8 + g, i3 = base + 12 + g;
        int u0 = __shfl(u_l, i0, 64), u1 = __shfl(u_l, i1, 64);
        int u2 = __shfl(u_l, i2, 64), u3 = __shfl(u_l, i3, 64);
        float w0 = __shfl(w_l, i0, 64), w1 = __shfl(w_l, i1, 64);
        float w2 = __shfl(w_l, i2, 64), w3 = __shfl(w_l, i3, 64);
        uint4 d0 = *(const uint4*)(h + (size_t)u0 * 128 + p * 8);
        uint4 d1 = *(const uint4*)(h + (size_t)u1 * 128 + p * 8);
        uint4 d2 = *(const uint4*)(h + (size_t)u2 * 128 + p * 8);
        uint4 d3 = *(const uint4*)(h + (size_t)u3 * 128 + p * 8);
        acc8(acc, d0, w0);
        acc8(acc, d1, w1);
        acc8(acc, d2, w2);
        acc8(acc, d3, w3);
    }

#pragma unroll
    for (int k = 0; k < 8; ++k) {
        float a = acc[k];
        a += __shfl_xor(a, 16, 64);
        a += __shfl_xor(a, 32, 64);
        acc[k] = a;
    }

    if (g == 0) {
        const unsigned* su = (const unsigned*)&selfr;
        float dv = rsqrtf((float)(dcl + 1));
        float dv2 = dv * dv;
        float o[8];
#pragma unroll
        for (int k = 0; k < 4; ++k) {
            float lo = __uint_as_float((su[k] & 0xFFFFu) << 16);
            float hi = __uint_as_float(su[k] & 0xFFFF0000u);
            o[2 * k]     = dv * acc[2 * k]     + lo * dv2;
            o[2 * k + 1] = dv * acc[2 * k + 1] + hi * dv2;
        }
        if (BIAS) {
            float4 bv0 = *(const float4*)&bias[p * 8];
            float4 bv1 = *(const float4*)&bias[p * 8 + 4];
            o[0] += bv0.x; o[1] += bv0.y; o[2] += bv0.z; o[3] += bv0.w;
            o[4] += bv1.x; o[5] += bv1.y; o[6] += bv1.z; o[7] += bv1.w;
        }
        if (RELU) {
#pragma unroll
            for (int k = 0; k < 8; ++k) o[k] = fmaxf(o[k], 0.f);
        }
        if (OUT_BF) {
            uint4 packed;
            unsigned* pu = (unsigned*)&packed;
#pragma unroll
            for (int k = 0; k < 4; ++k)
                pu[k] = (unsigned)f2b(o[2 * k]) | ((unsigned)f2b(o[2 * k + 1]) << 16);
            *(uint4*)((unsigned short*)y + (size_t)v * 128 + p * 8) = packed;
        } else {
            float* yf = (float*)y + (size_t)v * 128 + p * 8;
            *(float4*)yf = make_float4(o[0], o[1], o[2], o[3]);
            *(float4*)(yf + 4) = make_float4(o[4], o[5], o[6], o[7]);
        }
        if (STATS) {
#pragma unroll
            for (int k = 0; k < 8; ++k) sv[wid][p * 8 + k] = o[k];
        }
    }

    if (STATS) {
        __syncthreads();   // uniform: STATS is compile-time
        if (tid < 128) {
            float s = 0.f, q = 0.f;
#pragma unroll
            for (int w = 0; w < 4; ++w) {
                float val = sv[w][tid];
                s += val;
                q += val * val;
            }
            int slot = blockIdx.x & (NSLOTS - 1);
            atomicAdd(&sumP[slot * 128 + tid], s);
            atomicAdd(&sqP[slot * 128 + tid], q);
        }
    }
}

// ---------- MFMA bf16 GEMM (64x64, LDT=40), register-prefetched K loop ----------
template <bool RELU, bool STATS>
__global__ void __launch_bounds__(256) mfma_gemm_kernel(const unsigned short* __restrict__ A,
                                                        const unsigned short* __restrict__ Bt,
                                                        const float* __restrict__ bias,
                                                        unsigned short* __restrict__ C,
                                                        float* __restrict__ sums,
                                                        float* __restrict__ sumsqs,
                                                        int M, int N, int K) {
    const int LDT = 40;  // 32 + 8 pad (ushorts)
    __shared__ unsigned short As[64 * LDT];
    __shared__ unsigned short Bs[64 * LDT];
    int tid = threadIdx.x;
    int bm = blockIdx.x * 64;
    int bn = blockIdx.y * 64;
    int lr = tid >> 2;
    int lc = (tid & 3) * 8;
    int lane = tid & 63;
    int w = tid >> 6;
    int wr = (w >> 1) * 32, wc = (w & 1) * 32;
    int l15 = lane & 15, q = lane >> 4;

    f32x4 acc[2][2] = {};
    bool arow_ok = (bm + lr) < M;
    const unsigned short* Aptr = A + (size_t)(bm + lr) * K + lc;
    const unsigned short* Bptr = Bt + (size_t)(bn + lr) * K + lc;

    uint4 av = arow_ok ? *(const uint4*)(Aptr) : make_uint4(0u, 0u, 0u, 0u);
    uint4 bv = *(const uint4*)(Bptr);

    for (int k0 = 0; k0 < K; k0 += 32) {
        *(uint4*)&As[lr * LDT + lc] = av;
        *(uint4*)&Bs[lr * LDT + lc] = bv;
        __syncthreads();
        if (k0 + 32 < K) {   // prefetch next tile; latency hides under ds_read+MFMA
            av = arow_ok ? *(const uint4*)(Aptr + k0 + 32) : make_uint4(0u, 0u, 0u, 0u);
            bv = *(const uint4*)(Bptr + k0 + 32);
        }
        bf16x8 a0 = *(const bf16x8*)&As[(wr + 0 + l15) * LDT + q * 8];
        bf16x8 a1 = *(const bf16x8*)&As[(wr + 16 + l15) * LDT + q * 8];
        bf16x8 b0 = *(const bf16x8*)&Bs[(wc + 0 + l15) * LDT + q * 8];
        bf16x8 b1 = *(const bf16x8*)&Bs[(wc + 16 + l15) * LDT + q * 8];
        acc[0][0] = __builtin_amdgcn_mfma_f32_16x16x32_bf16(a0, b0, acc[0][0], 0, 0, 0);
        acc[0][1] = __builtin_amdgcn_mfma_f32_16x16x32_bf16(a0, b1, acc[0][1], 0, 0, 0);
        acc[1][0] = __builtin_amdgcn_mfma_f32_16x16x32_bf16(a1, b0, acc[1][0], 0, 0, 0);
        acc[1][1] = __builtin_amdgcn_mfma_f32_16x16x32_bf16(a1, b1, acc[1][1], 0, 0, 0);
        __syncthreads();
    }

    float scol[2] = {0.f, 0.f};
    float qcol[2] = {0.f, 0.f};
#pragma unroll
    for (int mi = 0; mi < 2; ++mi)
#pragma unroll
        for (int ni = 0; ni < 2; ++ni) {
            int colc = bn + wc + ni * 16 + l15;
            float bv2 = bias ? bias[colc] : 0.f;
#pragma unroll
            for (int r = 0; r < 4; ++r) {
                int row = bm + wr + mi * 16 + q * 4 + r;
                if (row < M) {
                    float vv = acc[mi][ni][r] + bv2;
                    if (RELU) vv = fmaxf(vv, 0.f);
                    C[(size_t)row * N + colc] = f2b(vv);
                    if (STATS) { scol[ni] += vv; qcol[ni] += vv * vv; }
                }
            }
        }

    if (STATS) {
        __shared__ float sred[4][2][16];
        __shared__ float qred[4][2][16];
#pragma unroll
        for (int ni = 0; ni < 2; ++ni) {
            float s = scol[ni], qq = qcol[ni];
            s += __shfl_xor(s, 16, 64);
            s += __shfl_xor(s, 32, 64);
            qq += __shfl_xor(qq, 16, 64);
            qq += __shfl_xor(qq, 32, 64);
            if (lane < 16) { sred[w][ni][l15] = s; qred[w][ni][l15] = qq; }
        }
        __syncthreads();
        if (tid < 64) {
            int par = (tid >> 5) & 1;
            int ni = (tid >> 4) & 1;
            int l = tid & 15;
            int slot = blockIdx.x & (GSLOTS - 1);
            atomicAdd(&sums[slot * HID_DIM + bn + tid],
                      sred[par][ni][l] + sred[par + 2][ni][l]);
            atomicAdd(&sumsqs[slot * HID_DIM + bn + tid],
                      qred[par][ni][l] + qred[par + 2][ni][l]);
        }
    }
}

// ---------- fold BN1 into W2 (8 blocks); reduces GSLOTS stat partials first ----------
__global__ void __launch_bounds__(256) prep2_kernel(const float* __restrict__ sum1P,
                                                    const float* __restrict__ sumsq1P,
                                                    const float* __restrict__ gamma1,
                                                    const float* __restrict__ beta1,
                                                    const float* __restrict__ W2,
                                                    unsigned short* __restrict__ W2pt,
                                                    float* __restrict__ bc2) {
    __shared__ float a1s[HID_DIM], s1s[HID_DIM];
    __shared__ float bp[16][17];
    int t = threadIdx.x;
    {
        float s = 0.f, q = 0.f;
#pragma unroll 8
        for (int j = 0; j < GSLOTS; ++j) {
            s += sum1P[j * HID_DIM + t];
            q += sumsq1P[j * HID_DIM + t];
        }
        float m = s * (1.f / N_NODES);
        float var = q * (1.f / N_NODES) - m * m;
        float a = gamma1[t] * rsqrtf(var + EPS);
        a1s[t] = a;
        s1s[t] = beta1[t] - m * a;
    }
    __syncthreads();
    int row = blockIdx.x * 16 + (t & 15);
    int ks = t >> 4;
    float bacc = 0.f;
    unsigned short wloc[16];
#pragma unroll
    for (int j = 0; j < 16; ++j) {
        int k = ks * 16 + j;
        float wv = W2[k * EMB_DIM + row];
        wloc[j] = f2b(a1s[k] * wv);
        bacc += s1s[k] * wv;
    }
    *(uint4*)&W2pt[(size_t)row * HID_DIM + ks * 16]     = *(uint4*)&wloc[0];
    *(uint4*)&W2pt[(size_t)row * HID_DIM + ks * 16 + 8] = *(uint4*)&wloc[8];
    bp[t & 15][ks] = bacc;
    __syncthreads();
    if (t < 16) {
        float s = 0.f;
#pragma unroll
        for (int g = 0; g < 16; ++g) s += bp[t][g];
        bc2[blockIdx.x * 16 + t] = s;
    }
}

// ---------- segmented max per graph; finalizes layer-2 partial stats in-block ----------
__global__ void __launch_bounds__(128) segmax_kernel(const float* __restrict__ y,
                                                     const float* __restrict__ sumP,
                                                     const float* __restrict__ sqP,
                                                     const float* __restrict__ gamma2,
                                                     const float* __restrict__ beta2,
                                                     const int* __restrict__ batch,
                                                     float* __restrict__ out) {
    __shared__ int sh[2];
    int g = blockIdx.x;
    int c = threadIdx.x;
    float s2 = 0.f, q2 = 0.f;
#pragma unroll 8
    for (int j = 0; j < NSLOTS; ++j) {
        s2 += sumP[j * 128 + c];
        q2 += sqP[j * 128 + c];
    }
    float mch = s2 * (1.f / N_NODES);
    float var = q2 * (1.f / N_NODES) - mch * mch;
    float ac = gamma2[c] * rsqrtf(var + EPS);
    float sc = beta2[c] - mch * ac;
    if (threadIdx.x == 0) {
        int lo = 0, hi = N_NODES;
        while (lo < hi) { int mid = (lo + hi) >> 1; if (batch[mid] < g) lo = mid + 1; else hi = mid; }
        sh[0] = lo;
        hi = N_NODES;
        while (lo < hi) { int mid = (lo + hi) >> 1; if (batch[mid] < g + 1) lo = mid + 1; else hi = mid; }
        sh[1] = lo;
    }
    __syncthreads();
    int beg = sh[0], end = sh[1];
    float m = -INFINITY;
    for (int v = beg; v < end; ++v) {
        m = fmaxf(m, fmaf(ac, y[(size_t)v * EMB_DIM + c], sc));
    }
    out[(size_t)g * EMB_DIM + c] = m;
}

extern "C" void kernel_launch(void* const* d_in, const int* in_sizes, int n_in,
                              void* d_out, int out_size, void* d_ws, size_t ws_size,
                              hipStream_t stream) {
    const float* x      = (const float*)d_in[0];
    const int*   ei     = (const int*)d_in[1];
    const int*   batch  = (const int*)d_in[2];
    const float* W1     = (const float*)d_in[3];
    const float* b1     = (const float*)d_in[4];
    const float* gamma1 = (const float*)d_in[5];
    const float* beta1  = (const float*)d_in[6];
    const float* W2     = (const float*)d_in[7];
    const float* b2     = (const float*)d_in[8];
    const float* gamma2 = (const float*)d_in[9];
    const float* beta2  = (const float*)d_in[10];
    float* out = (float*)d_out;

    char* ws = (char*)d_ws;
    size_t off = 0;
    auto alloc = [&](size_t bytes) -> char* {
        char* p = ws + off;
        off = (off + bytes + 255) & ~(size_t)255;
        return p;
    };
    int*   fill    = (int*)alloc((size_t)N_NODES * 4);
    float* gsumP   = (float*)alloc((size_t)GSLOTS * HID_DIM * 4);  // layer-1 stat partials
    float* gsqP    = (float*)alloc((size_t)GSLOTS * HID_DIM * 4);
    float* sumP    = (float*)alloc((size_t)NSLOTS * 128 * 4);      // layer-2 stat partials
    float* sqP     = (float*)alloc((size_t)NSLOTS * 128 * 4);
    size_t zbytes = off;
    int*   col    = (int*)alloc((size_t)N_NODES * ELLW * 4);
    float* bc2    = (float*)alloc((size_t)EMB_DIM * 4);
    unsigned short* W1t  = (unsigned short*)alloc((size_t)HID_DIM * IN_DIM * 2);
    unsigned short* W2pt = (unsigned short*)alloc((size_t)HID_DIM * EMB_DIM * 2);
    unsigned short* xbf  = (unsigned short*)alloc((size_t)N_NODES * IN_DIM * 2);   // also y2 region
    unsigned short* axbf = (unsigned short*)alloc((size_t)N_NODES * IN_DIM * 2);
    unsigned short* y1bf = (unsigned short*)alloc((size_t)N_NODES * HID_DIM * 2);
    unsigned short* gbf  = (unsigned short*)alloc((size_t)N_NODES * EMB_DIM * 2);
    float* y2 = (float*)xbf;  // xbf+axbf dead by layer 2; contiguous 25.6 MB
    (void)ws_size; (void)in_sizes; (void)n_in; (void)out_size;

    const int* src  = ei;
    const int* dstp = ei + N_EDGES;

    hipMemsetAsync(ws, 0, zbytes, stream);   // zero fill + all stat partials in one call

    // merged: ELL scatter + x->bf16 + W1 transpose
    scatter_convert<<<SCAT_BLOCKS + F2B_BLOCKS + TW1_BLOCKS, 256, 0, stream>>>(
        src, dstp, fill, col, x, xbf, W1, W1t);

    // Layer 1: ax = A x (bf16), y1 = relu(ax@W1 + b1) (bf16) with slotted column stats
    aggw_kernel<false, true, false, false><<<N_NODES / 4, 256, 0, stream>>>(
        xbf, fill, col, nullptr, axbf, nullptr, nullptr);
    dim3 g1((N_NODES + 63) / 64, HID_DIM / 64);
    mfma_gemm_kernel<true, true><<<g1, 256, 0, stream>>>(axbf, W1t, b1, y1bf,
                                                         gsumP, gsqP,
                                                         N_NODES, HID_DIM, IN_DIM);

    // Fold BN1 into W2 (transposed bf16) + pre-aggregation column bias bc2
    prep2_kernel<<<8, 256, 0, stream>>>(gsumP, gsqP, gamma1, beta1, W2, W2pt, bc2);

    // Layer 2: g = y1@W2p + bc2 (bf16), y2 = relu(A g + b2) (fp32) with slotted stats
    dim3 g2((N_NODES + 63) / 64, EMB_DIM / 64);
    mfma_gemm_kernel<false, false><<<g2, 256, 0, stream>>>(y1bf, W2pt, bc2, gbf,
                                                           nullptr, nullptr,
                                                           N_NODES, EMB_DIM, HID_DIM);
    aggw_kernel<true, false, true, true><<<N_NODES / 4, 256, 0, stream>>>(
        gbf, fill, col, b2, y2, sumP, sqP);

    // fused BN2-finalize (reduce NSLOTS partials) + per-graph segmented max
    segmax_kernel<<<N_GRAPHS, 128, 0, stream>>>(y2, sumP, sqP,
                                                gamma2, beta2, batch, out);
}